// Round 16
// baseline (22.584 us; speedup 1.0000x reference)
//
#include <hip/hip_runtime.h>

typedef __attribute__((ext_vector_type(8)))  short short8;
typedef __attribute__((ext_vector_type(16))) float f32x16;

#define BATCH 8
#define NPTS  4096
#define TPB   1024            // 16 waves = 4/SIMD; wave-pairs split the tile loop
#define NQG   16              // query groups of 256 per (dir,b)
#define ONEB  0x3F80u         // bf16(1.0)
#define BIASB 0x4080u         // bf16(4.0)
#define BIASF 4.0f

// round-to-nearest-even f32 -> bf16 bits
__device__ __forceinline__ unsigned bfr(float f) {
    unsigned u = __float_as_uint(f);
    return (u + 0x7FFFu + ((u >> 16) & 1u)) >> 16;
}
__device__ __forceinline__ float ubf(unsigned s) {
    return __uint_as_float(s << 16);
}

// One-kernel MFMA chamfer (r15 structure, verified absmax 0.0).
// P[r][c] = |t_r - q_c|^2 + BIAS via K=16 rank factorization; hi terms in
// k0-7 (lanes<32), lo terms in k8-15 (lanes>=32) -> 1 mfma_32x32x16_bf16
// per 32x32 tile; min-reduce in registers with v_min3_f32.
// Round-16 deltas (latency attack):
//  - 16 waves (4/SIMD): wave w and w+8 share one B-frag (32 queries) and
//    split the 128 target tiles 64/64; partials merged via 2KB LDS fmin.
//  - tile loop unrolled 4x: 4 batched ds_read_b128 (imm offsets) ahead of
//    4 MFMAs, TWO independent min3 accumulator chains (halved dep chain).
__global__ __launch_bounds__(TPB) void chamfer_mfma(
    const float* __restrict__ preds,
    const float* __restrict__ gts,
    float* __restrict__ out)
{
    const int blk = blockIdx.x;
    const int qg  = blk & 15;
    const int db  = blk >> 4;        // dir*8 + b
    const int dir = db >> 3;
    const int b   = db & 7;

    const float* Q = dir ? gts   : preds;   // query set (output-indexed)
    const float* T = dir ? preds : gts;     // target set (min'd over)

    __shared__ uint4 sA[2 * NPTS];   // [half][row] A-frags, 128 KiB
    __shared__ float sM[16][32];     // per-wave partial col-mins, 2 KiB
    __shared__ float red[8];

    const size_t bbase = (size_t)b * NPTS;
    const int lane = threadIdx.x & 63;
    const int wid  = threadIdx.x >> 6;   // 0..15
    const int la   = lane & 31;
    const int h    = lane >> 5;          // 0: k0-7 (hi), 1: k8-15 (lo)
    const int qw   = wid & 7;            // query sub-group owner
    const int th   = wid >> 3;           // tile half (0: tiles 0-63, 1: 64-127)

    // ---- stage all 4096 target rows as A-frags (4 rows/thread,
    // lane-consecutive 16B ds_writes -> conflict-free)
    for (int j = 0; j < 4; ++j) {
        const int r = threadIdx.x + j * TPB;
        const float* tp = T + (bbase + r) * 3;
        const float X = tp[0], Y = tp[1], Z = tp[2];
        const float px = -2.f * X, py = -2.f * Y, pz = -2.f * Z;
        const float rt = fmaf(X, X, fmaf(Y, Y, Z * Z));
        const unsigned pxh = bfr(px), pyh = bfr(py), pzh = bfr(pz);
        const unsigned pxl = bfr(px - ubf(pxh)), pyl = bfr(py - ubf(pyh)),
                       pzl = bfr(pz - ubf(pzh));
        const unsigned rth = bfr(rt), rtl = bfr(rt - ubf(rth));
        sA[r]        = make_uint4(pxh | (pyh << 16), pzh | (rth << 16),
                                  rtl | (ONEB << 16), ONEB | (ONEB << 16));
        sA[NPTS + r] = make_uint4(pxl | (pyl << 16), pzl | (pxh << 16),
                                  pyh | (pzh << 16), 0u);
    }

    // ---- this lane's B-frag: query col c, half h
    short8 bfrag;
    {
        const int c = qg * 256 + qw * 32 + la;
        const float* qp = Q + (bbase + c) * 3;
        const float X = qp[0], Y = qp[1], Z = qp[2];
        const float rq = fmaf(X, X, fmaf(Y, Y, Z * Z));
        const unsigned xh = bfr(X), yh = bfr(Y), zh = bfr(Z);
        const unsigned xl = bfr(X - ubf(xh)), yl = bfr(Y - ubf(yh)),
                       zl = bfr(Z - ubf(zh));
        const unsigned rqh = bfr(rq), rql = bfr(rq - ubf(rqh));
        const uint4 b1 = make_uint4(xh | (yh << 16), zh | (ONEB << 16),
                                    ONEB | (rqh << 16), rql | (BIASB << 16));
        const uint4 b2 = make_uint4(xh | (yh << 16), zh | (xl << 16),
                                    yl | (zl << 16), 0u);
        bfrag = __builtin_bit_cast(short8, h ? b2 : b1);
    }

    __syncthreads();

    // ---- main loop: 64 tiles per wave, 4 per iter, 2 independent chains
    const f32x16 zacc = {};
    f32x16 maccA, maccB;
    #pragma unroll
    for (int i = 0; i < 16; ++i) { maccA[i] = 3.4e38f; maccB[i] = 3.4e38f; }

    const uint4* aBase = sA + h * NPTS + la + th * (64 * 32);
    for (int t = 0; t < 64; t += 4) {
        const uint4 A0 = aBase[t * 32];
        const uint4 A1 = aBase[t * 32 + 32];
        const uint4 A2 = aBase[t * 32 + 64];
        const uint4 A3 = aBase[t * 32 + 96];
        const f32x16 p0 = __builtin_amdgcn_mfma_f32_32x32x16_bf16(
            __builtin_bit_cast(short8, A0), bfrag, zacc, 0, 0, 0);
        const f32x16 p1 = __builtin_amdgcn_mfma_f32_32x32x16_bf16(
            __builtin_bit_cast(short8, A1), bfrag, zacc, 0, 0, 0);
        #pragma unroll
        for (int i = 0; i < 16; ++i)
            maccA[i] = fminf(fminf(p0[i], p1[i]), maccA[i]);   // v_min3_f32
        const f32x16 p2 = __builtin_amdgcn_mfma_f32_32x32x16_bf16(
            __builtin_bit_cast(short8, A2), bfrag, zacc, 0, 0, 0);
        const f32x16 p3 = __builtin_amdgcn_mfma_f32_32x32x16_bf16(
            __builtin_bit_cast(short8, A3), bfrag, zacc, 0, 0, 0);
        #pragma unroll
        for (int i = 0; i < 16; ++i)
            maccB[i] = fminf(fminf(p2[i], p3[i]), maccB[i]);
    }

    // ---- epilogue: merge chains, min over 16 row-slots, fold lane halves
    const float e0  = fminf(maccA[0],  maccB[0]);
    const float e1  = fminf(maccA[1],  maccB[1]);
    const float e2  = fminf(maccA[2],  maccB[2]);
    const float e3  = fminf(maccA[3],  maccB[3]);
    const float e4  = fminf(maccA[4],  maccB[4]);
    const float e5  = fminf(maccA[5],  maccB[5]);
    const float e6  = fminf(maccA[6],  maccB[6]);
    const float e7  = fminf(maccA[7],  maccB[7]);
    const float e8  = fminf(maccA[8],  maccB[8]);
    const float e9  = fminf(maccA[9],  maccB[9]);
    const float e10 = fminf(maccA[10], maccB[10]);
    const float e11 = fminf(maccA[11], maccB[11]);
    const float e12 = fminf(maccA[12], maccB[12]);
    const float e13 = fminf(maccA[13], maccB[13]);
    const float e14 = fminf(maccA[14], maccB[14]);
    const float e15 = fminf(maccA[15], maccB[15]);
    const float g0 = fminf(fminf(e0,  e1),  e2);
    const float g1 = fminf(fminf(e3,  e4),  e5);
    const float g2 = fminf(fminf(e6,  e7),  e8);
    const float g3 = fminf(fminf(e9,  e10), e11);
    const float g4 = fminf(fminf(e12, e13), e14);
    float m = fminf(fminf(fminf(g0, g1), fminf(g2, g3)), fminf(g4, e15));
    m = fminf(m, __shfl_xor(m, 32, 64));

    // ---- merge wave-pair tile halves via LDS, then block sum, one atomic
    if (lane < 32) sM[wid][la] = m;
    __syncthreads();

    float s = 0.0f;
    if (wid < 8) {
        if (lane < 32)
            s = fminf(sM[wid][la], sM[wid + 8][la]) - BIASF;
        #pragma unroll
        for (int off = 16; off > 0; off >>= 1)
            s += __shfl_down(s, off, 64);
        if (lane == 0) red[wid] = s;
    }
    __syncthreads();
    if (threadIdx.x == 0) {
        float tsum = 0.0f;
        #pragma unroll
        for (int w = 0; w < 8; ++w) tsum += red[w];
        atomicAdd(out, tsum);
    }
}

extern "C" void kernel_launch(void* const* d_in, const int* in_sizes, int n_in,
                              void* d_out, int out_size, void* d_ws, size_t ws_size,
                              hipStream_t stream) {
    const float* preds = (const float*)d_in[0];
    const float* gts   = (const float*)d_in[1];
    float* out = (float*)d_out;

    hipMemsetAsync(out, 0, sizeof(float), stream);
    chamfer_mfma<<<dim3(2 * BATCH * NQG), TPB, 0, stream>>>(preds, gts, out);
}